// Round 8
// baseline (90.098 us; speedup 1.0000x reference)
//
#include <hip/hip_runtime.h>

#define BLOCK 8
#define NGRID 512

// ---------------------------------------------------------------------------
// Compile-time replication of
//   np.random.RandomState(0).choice(np.array([1.0,3.0],f32), size=(512,8))
// (MT19937 legacy scalar seeding, one 32-bit draw per value, value = draw&1).
// Bit i of pattern byte = element i: g[i] = bit ? 3.0f : 1.0f.
// Dedup (first occurrence) is argmax-neutral. kenc = 255 - dedup_index, so
// "ties -> max kenc" == numpy first-max. Scan order = bit-reversed ascending
// (maximizes shared low-bit spine prefixes); selection is order-independent.
// ---------------------------------------------------------------------------
struct Sched {
  int nd;                      // distinct patterns (222)
  unsigned char kpat[256];     // kenc -> pattern byte (epilogue gather)
  unsigned char dfs_pat[256];  // scan ordinal -> pattern byte
  unsigned char dfs_ken[256];  // scan ordinal -> kenc
  unsigned char lowbit[256];   // ordinal -> lowest differing bit vs prev (0 for j=0)
  unsigned char csn[32];       // chunk -> member count (chunks of 8)
  unsigned char cslot[32][8];  // chunk, i -> slot (ordinal & 7), kenc-ascending
  unsigned char cken[32][8];   // chunk, i -> kenc,                kenc-ascending
};

constexpr unsigned char bitrev8c(unsigned v) {
  unsigned r = 0;
  for (int i = 0; i < 8; ++i) r |= ((v >> i) & 1u) << (7 - i);
  return (unsigned char)r;
}
constexpr int popcount8c(int v) {
  int p = 0;
  for (int i = 0; i < 8; ++i) p += (v >> i) & 1;
  return p;
}
constexpr int ctz8c(int v) {
  for (int i = 0; i < 8; ++i) if ((v >> i) & 1) return i;
  return 0;
}

constexpr Sched make_sched() {
  Sched t{};
  bool exists[256] = {};
  unsigned char kenc[256] = {};
  // --- MT19937, numpy legacy scalar seed 0 ---
  unsigned mt[624] = {};
  {
    unsigned s = 0u;
    for (int i = 0; i < 624; ++i) {
      mt[i] = s;
      s = 1812433253u * (s ^ (s >> 30)) + (unsigned)(i + 1);
    }
  }
  int pos = 624;
  int nd = 0;
  for (int j = 0; j < NGRID; ++j) {
    unsigned char b = 0;
    for (int i = 0; i < BLOCK; ++i) {
      if (pos == 624) {
        for (int k = 0; k < 624; ++k) {
          int k1 = (k + 1 < 624) ? k + 1 : 0;
          int k397 = (k + 397 < 624) ? k + 397 : k + 397 - 624;
          unsigned y = (mt[k] & 0x80000000u) | (mt[k1] & 0x7fffffffu);
          unsigned v = mt[k397] ^ (y >> 1);
          if (y & 1u) v ^= 0x9908b0dfu;
          mt[k] = v;
        }
        pos = 0;
      }
      unsigned y = mt[pos++];
      y ^= y >> 11;
      y ^= (y << 7) & 0x9d2c5680u;
      y ^= (y << 15) & 0xefc60000u;
      y ^= y >> 18;
      if (y & 1u) b |= (unsigned char)(1u << i);
    }
    if (!exists[b]) {
      exists[b] = true;
      kenc[b] = (unsigned char)(255 - nd);
      t.kpat[255 - nd] = b;
      ++nd;
    }
  }
  t.nd = nd;
  // --- scan order: bit-reversed ascending ---
  int m = 0;
  for (int r = 0; r < 256; ++r) {
    unsigned char b = bitrev8c((unsigned)r);
    if (exists[b]) {
      t.dfs_pat[m] = b;
      t.dfs_ken[m] = kenc[b];
      ++m;
    }
  }
  t.lowbit[0] = 0;
  for (int j = 1; j < nd; ++j)
    t.lowbit[j] = (unsigned char)ctz8c(t.dfs_pat[j] ^ t.dfs_pat[j - 1]);
  // --- chunks of 8, members sorted by kenc ascending (insertion sort) ---
  int nc = (nd + 7) / 8;
  for (int c = 0; c < nc; ++c) {
    int n = nd - 8 * c; if (n > 8) n = 8;
    t.csn[c] = (unsigned char)n;
    unsigned char sl[8] = {}, ke[8] = {};
    for (int i = 0; i < n; ++i) { sl[i] = (unsigned char)i; ke[i] = t.dfs_ken[8 * c + i]; }
    for (int i = 1; i < n; ++i) {
      unsigned char ks = ke[i], ss = sl[i];
      int p = i - 1;
      while (p >= 0 && ke[p] > ks) { ke[p + 1] = ke[p]; sl[p + 1] = sl[p]; --p; }
      ke[p + 1] = ks; sl[p + 1] = ss;
    }
    for (int i = 0; i < n; ++i) { t.cslot[c][i] = sl[i]; t.cken[c][i] = ke[i]; }
  }
  return t;
}

constexpr Sched SC = make_sched();
constexpr int ND = SC.nd;
static_assert(ND > 168 && ND <= 224, "section layout assumes 22..28 chunks");

// chunk-local winner index -> kenc, packed 8 bytes into a u64 (compile time)
constexpr unsigned long long pack_klut(int c) {
  unsigned long long v = 0ull;
  for (int i = 0; i < 8; ++i)
    v |= (unsigned long long)SC.cken[c][i] << (8 * i);
  return v;
}

// ---------------------------------------------------------------------------
// Compile-time cost-balanced section cuts (chunk-aligned). Cost model per
// leaf: spine fma (8 - lowbit) + dd (1) + score (1 for pow2 classes, 3 for
// Markstein) + flat 27 per chunk-close. Wave 0 takes the LAST run and also
// the merge+epilogue (~60 inst), so runs 1-3 target (total+60)/4 each and
// wave 0 gets the remainder. This equalizes the barrier-gating wave.
// ---------------------------------------------------------------------------
struct Cuts { int k1, k2, k3; };
constexpr Cuts make_cuts() {
  int nc = (ND + 7) / 8;
  int cost[32] = {};
  int total = 0;
  for (int c = 0; c < nc; ++c) {
    int jend = (8 * c + 8 < ND) ? 8 * c + 8 : ND;
    int cc = 27;
    for (int j = 8 * c; j < jend; ++j) {
      int p0 = (j == 0) ? 0 : SC.lowbit[j];
      cc += (8 - p0) + 1;
      int pc = popcount8c(SC.dfs_pat[j]);
      cc += (pc == 0 || pc == 1 || pc == 3 || pc == 7) ? 1 : 3;
    }
    cost[c] = cc;
    total += cc;
  }
  int g = (total + 60) / 4;
  Cuts r{0, 0, 0};
  int acc = 0, c = 0;
  for (; c < nc; ++c) { acc += cost[c]; if (acc >= g) { r.k1 = c + 1; break; } }
  acc = 0;
  for (c = r.k1; c < nc; ++c) { acc += cost[c]; if (acc >= g) { r.k2 = c + 1; break; } }
  acc = 0;
  for (c = r.k2; c < nc; ++c) { acc += cost[c]; if (acc >= g) { r.k3 = c + 1; break; } }
  if (r.k1 < 1) r.k1 = 7;
  if (r.k2 <= r.k1) r.k2 = r.k1 + 7;
  if (r.k3 <= r.k2) r.k3 = r.k2 + 7;
  if (r.k3 >= nc) r.k3 = nc - 1;
  return r;
}
constexpr Cuts CUT = make_cuts();
constexpr int K1 = CUT.k1 * 8;
constexpr int K2 = CUT.k2 * 8;
constexpr int K3 = CUT.k3 * 8;
static_assert(K1 > 0 && K2 > K1 && K3 > K2 && K3 < ND, "cut sanity");

// epilogue gather table: kenc -> pattern byte (L1-resident)
__device__ __constant__ const unsigned char g_pat[256] = {
#define P1(z) SC.kpat[z]
#define P8(z) P1(z), P1(z+1), P1(z+2), P1(z+3), P1(z+4), P1(z+5), P1(z+6), P1(z+7)
#define P64(z) P8(z), P8(z+8), P8(z+16), P8(z+24), P8(z+32), P8(z+40), P8(z+48), P8(z+56)
    P64(0), P64(64), P64(128), P64(192)
#undef P64
#undef P8
#undef P1
};

// ---------------------------------------------------------------------------
// Sectioned trie scan step (proven R0/R7 body, bounded to [J0, JEND)).
// Chain values are scan-path-independent: recomputing all 8 spine levels at
// a section start (p0=0 at J==J0) yields bit-identical leaf d values, hence
// bit-identical scores (exact pow2 scale or Markstein CR division).
// Sections are chunk-aligned (J0 % 8 == 0), so chunk-close logic is global.
// ---------------------------------------------------------------------------
template <int J, int J0, int JEND>
struct Step {
  static __device__ __forceinline__ void run(const float (&a)[BLOCK], float (&sp)[9],
                                             float (&scs)[8], float &gb, int &gk) {
    constexpr int pat = SC.dfs_pat[J];
    constexpr int p0 = (J == J0) ? 0 : SC.lowbit[J];
#pragma unroll
    for (int l = 0; l < 8; ++l) {
      if (l >= p0) {
        if ((pat >> l) & 1)
          sp[l + 1] = __builtin_fmaf(a[l], 3.0f, sp[l]);
        else
          sp[l + 1] = sp[l] + a[l];
      }
    }
    float d = sp[8];
    float dd = d * d;
    constexpr int pc = popcount8c(pat);
    float sc;
    if constexpr (pc == 0)      sc = dd * 0.125f;      // /8   exact
    else if constexpr (pc == 1) sc = dd * 0.0625f;     // /16  exact
    else if constexpr (pc == 3) sc = dd * 0.03125f;    // /32  exact
    else if constexpr (pc == 7) sc = dd * 0.015625f;   // /64  exact
    else {
      constexpr float nf = (float)(8 * (1 + pc));
      constexpr float rcf = 1.0f / nf;                 // RN reciprocal (compile time)
      float q0 = dd * rcf;
      float r = __builtin_fmaf(-nf, q0, dd);           // exact residual
      sc = __builtin_fmaf(r, rcf, q0);                 // Markstein: == fl32(dd/nf)
    }
    scs[J & 7] = sc;

    if constexpr (((J & 7) == 7) || (J == ND - 1)) {
      constexpr int c = J >> 3;
      constexpr int n = SC.csn[c];
      float cm;
      if constexpr (n == 8) {
        cm = __builtin_fmaxf(
            __builtin_fmaxf(__builtin_fmaxf(scs[0], scs[1]), __builtin_fmaxf(scs[2], scs[3])),
            __builtin_fmaxf(__builtin_fmaxf(scs[4], scs[5]), __builtin_fmaxf(scs[6], scs[7])));
      } else {
        cm = scs[0];
#pragma unroll
        for (int i = 1; i < n; ++i) cm = __builtin_fmaxf(cm, scs[i]);
      }
      int ck = 0;
#pragma unroll
      for (int i = 0; i < n; ++i)   // kenc ascending: last write = min original k
        ck = (scs[SC.cslot[c][i]] == cm) ? i : ck;     // i is an inline constant
      constexpr unsigned long long klut = pack_klut(c);
      int kenc = (int)((unsigned)(klut >> (ck << 3)) & 0xFFu);
      bool r = (cm > gb) || ((cm == gb) && (kenc > gk));
      gb = r ? cm : gb;
      gk = r ? kenc : gk;
    }
    if constexpr (J + 1 < JEND) Step<J + 1, J0, JEND>::run(a, sp, scs, gb, gk);
  }
};

#define SETS_PER_WG 4

// ---------------------------------------------------------------------------
// R8: R7's wave-sectioned trie with the three barrier-path overheads removed:
//  (1) double-buffered LDS staging -> 2 barriers/set (was 3); the next-set
//      stage overlaps wave 0's merge+epilogue instead of serializing after it;
//  (2) compile-time cost-balanced sections (constexpr partitioner) so all 4
//      waves reach the publish barrier together; wave 0 (merge+epilogue duty)
//      gets a correspondingly lighter section;
//  (3) prologue load-ahead retained (depth-1 async stage).
// Scan ops, selection, tie-break, epilogue: op-for-op the proven R0/R7
// sequence (absmax 0.0078125). Cross-wave argmax via LDS (score,kenc)
// partials; lexicographic merge is associative, kenc is a global priority.
// ---------------------------------------------------------------------------
__global__ __launch_bounds__(256, 8) void _IQ2XSQuantWeight_12945031430379_kernel(
    const float* __restrict__ w, float* __restrict__ out, int nsets) {
  __shared__ float lds_w[2][64 * 9];         // raw w, double-buffered
  __shared__ unsigned lds_part[4 * 64 * 2];  // per-wave (score bits, kenc)

  const int tid = threadIdx.x;
  const int lane = tid & 63;
  const int wid = tid >> 6;
  const int setBase = blockIdx.x * SETS_PER_WG;

  const uint2* gw = reinterpret_cast<const uint2*>(w);
  const int blk = tid >> 2, e = (tid & 3) * 2;

  // prologue: load + stage set 0, then issue set 1's loads
  uint2 sreg = {0u, 0u};
  if (setBase < nsets) {
    uint2 s0 = gw[(size_t)setBase * 256 + tid];
    lds_w[0][blk * 9 + e]     = __uint_as_float(s0.x);
    lds_w[0][blk * 9 + e + 1] = __uint_as_float(s0.y);
  }
  if (setBase + 1 < nsets) sreg = gw[(size_t)(setBase + 1) * 256 + tid];

  for (int s = 0; s < SETS_PER_WG; ++s) {
    if (setBase + s >= nsets) break;  // WG-uniform
    const int cur = s & 1;

    __syncthreads();  // barA: stage(cur) visible; part[] free (merge done)

    // ---- scan phase: wave 'wid' scans its balanced section ----
    float a[BLOCK];
#pragma unroll
    for (int i = 0; i < BLOCK; ++i)
      a[i] = __uint_as_float(__float_as_uint(lds_w[cur][lane * 9 + i]) & 0x7fffffffu);
    // stride-9 ds_read_b32: bank = (9*lane+i)%32, 9 odd -> conflict-free

    float sp[9];
    sp[0] = 0.0f;
    float scs[8];
    float gb = -1.0f;
    int gk = 0;
    // wave-uniform dispatch (no lane divergence); wave0 = last (lightest) run
    if (wid == 0)      Step<K3, K3, ND>::run(a, sp, scs, gb, gk);
    else if (wid == 1) Step<0,  0,  K1>::run(a, sp, scs, gb, gk);
    else if (wid == 2) Step<K1, K1, K2>::run(a, sp, scs, gb, gk);
    else               Step<K2, K2, K3>::run(a, sp, scs, gb, gk);

    lds_part[(wid * 64 + lane) * 2]     = __float_as_uint(gb);
    lds_part[(wid * 64 + lane) * 2 + 1] = (unsigned)gk;
    __syncthreads();  // barB: partials visible

    // ---- wave 0: merge + epilogue; waves 1-3: stage next set meanwhile ----
    if (wid == 0) {
      float best = __uint_as_float(lds_part[lane * 2]);
      int bk = (int)lds_part[lane * 2 + 1];
#pragma unroll
      for (int p = 1; p < 4; ++p) {
        float c = __uint_as_float(lds_part[(p * 64 + lane) * 2]);
        int ck = (int)lds_part[(p * 64 + lane) * 2 + 1];
        bool r = (c > best) || ((c == best) && (ck > bk));
        best = r ? c : best;
        bk = r ? ck : bk;
      }

      // epilogue: op-for-op the proven R0..R7 sequence (absmax 0.0078125)
      unsigned bits = (unsigned)g_pat[bk];

      float wv[BLOCK], av[BLOCK];
#pragma unroll
      for (int i = 0; i < BLOCK; ++i) {
        wv[i] = lds_w[cur][lane * 9 + i];
        av[i] = __uint_as_float(__float_as_uint(wv[i]) & 0x7fffffffu);
      }

      float q[BLOCK];
#pragma unroll
      for (int i = 0; i < BLOCK; ++i) q[i] = ((bits >> i) & 1u) ? 3.0f : 1.0f;

      float p[BLOCK];
#pragma unroll
      for (int i = 0; i < BLOCK; ++i) p[i] = av[i] * q[i];
      float num = ((p[0] + p[1]) + (p[2] + p[3])) + ((p[4] + p[5]) + (p[6] + p[7]));

      int popc = __popc(bits);
      float normf = (float)(8 + (popc << 3));
      float scale = num / normf;  // IEEE CR f32 divide (once)

      float o[BLOCK];
#pragma unroll
      for (int i = 0; i < BLOCK; ++i) {
        float sg = (wv[i] > 0.0f) ? 1.0f : ((wv[i] < 0.0f) ? -1.0f : 0.0f);
        float deq = (scale * q[i]) * sg;
        o[i] = wv[i] + (deq - wv[i]);  // w + stop_gradient(deq - w)
      }

      float4 o0 = {o[0], o[1], o[2], o[3]};
      float4 o1 = {o[4], o[5], o[6], o[7]};
      float4* op = reinterpret_cast<float4*>(out) +
                   ((size_t)(setBase + s) * 64 + lane) * 2;
      op[0] = o0;
      op[1] = o1;
    }

    // stage next set into the OTHER buffer (no barrier needed vs epilogue:
    // disjoint LDS regions; barA(s+1) orders it before next scan)
    if (s + 1 < SETS_PER_WG && setBase + s + 1 < nsets) {
      lds_w[cur ^ 1][blk * 9 + e]     = __uint_as_float(sreg.x);
      lds_w[cur ^ 1][blk * 9 + e + 1] = __uint_as_float(sreg.y);
      if (setBase + s + 2 < nsets)
        sreg = gw[(size_t)(setBase + s + 2) * 256 + tid];
    }
  }
}

extern "C" void kernel_launch(void* const* d_in, const int* in_sizes, int n_in,
                              void* d_out, int out_size, void* d_ws, size_t ws_size,
                              hipStream_t stream) {
  (void)n_in; (void)d_ws; (void)ws_size; (void)out_size;
  const float* w = (const float*)d_in[0];
  float* out = (float*)d_out;
  int n = in_sizes[0];
  int nsets = n / 512;  // 64 blocks x 8 elems per set (4.19M -> 8192 sets)
  int blocks = (nsets + SETS_PER_WG - 1) / SETS_PER_WG;
  _IQ2XSQuantWeight_12945031430379_kernel<<<blocks, 256, 0, stream>>>(w, out, nsets);
}